// Round 14
// baseline (784.788 us; speedup 1.0000x reference)
//
#include <hip/hip_runtime.h>
#include <hip/hip_bf16.h>

typedef __hip_bfloat16 bf16;
typedef __attribute__((ext_vector_type(8))) short short8;
typedef __attribute__((ext_vector_type(4))) float float4v;

#define Nn   50000
#define Ee   800000
#define E2   850000
#define Bb   128
#define NFd  7
#define HID  128
#define OUTD 64
#define EPS  1e-5f
#define SLOPE 0.2f
#define LOG2E 1.4426950408889634f
#define NSTRIP 3125          // Nn/16
#define NPAIR  1563          // ceil(NSTRIP/2)
#define WPREP_T 57344        // 3*256*64 + 128*64 threads for weight prep

#define MFMA16(a,b,c) __builtin_amdgcn_mfma_f32_16x16x32_bf16(a,b,c,0,0,0)

__device__ __forceinline__ float lane_bcast(float v, int l){
  return __int_as_float(__builtin_amdgcn_readlane(__float_as_int(v), l));
}
__device__ __forceinline__ float wred_sum(float v){
  #pragma unroll
  for (int o=32;o;o>>=1) v += __shfl_xor(v, o, 64);
  return v;
}
// compiler-managed DPP helpers (hazard-safe)
#define UPD_DPP(x, ctrl) \
  __int_as_float(__builtin_amdgcn_update_dpp(0, __float_as_int(x), (ctrl), 0xf, 0xf, false))
// sum over each 4-lane quad (quad == attention head group)
__device__ __forceinline__ float red4_quad(float x){
  x = x + UPD_DPP(x, 0xB1);  // quad_perm [1,0,3,2]
  x = x + UPD_DPP(x, 0x4E);  // quad_perm [2,3,0,1]
  return x;
}
__device__ __forceinline__ unsigned fkey(float f){
  unsigned u = __float_as_uint(f);
  return (u & 0x80000000u) ? ~u : (u | 0x80000000u);
}
__device__ __forceinline__ float fkeyinv(unsigned k){
  unsigned u = (k & 0x80000000u) ? (k ^ 0x80000000u) : ~k;
  return __uint_as_float(u);
}
__device__ __forceinline__ float tanh_fast(float x){
  float e = __expf(fminf(fmaxf(2.f*x, -30.f), 30.f));
  return (e-1.f)/(e+1.f);
}
__device__ __forceinline__ float bf_lo(unsigned u){ return __uint_as_float(u<<16); }
__device__ __forceinline__ float bf_hi(unsigned u){ return __uint_as_float(u & 0xffff0000u); }
__device__ __forceinline__ unsigned short f2bs(float f){
  bf16 h = __float2bfloat16(f);
  return *reinterpret_cast<unsigned short*>(&h);
}
__device__ __forceinline__ unsigned pack2(float a, float b){
  return (unsigned)f2bs(a) | ((unsigned)f2bs(b) << 16);
}
// bijective XCD swizzle (m204): contiguous chunk per XCD
__device__ __forceinline__ int xcd_swizzle(int bid, int nwg){
  int q = nwg >> 3, r = nwg & 7;
  int x = bid & 7, i = bid >> 3;
  return (x < r ? x*(q+1) : r*(q+1) + (x-r)*q) + i;
}

// ---------------- prep: pre-swizzled W images + per-graph ranges ------------
__global__ __launch_bounds__(256) void k_prep(
    const float* __restrict__ gWsrc, const float* __restrict__ gWdst,
    const float* __restrict__ pW1, const int* __restrict__ batch,
    unsigned* __restrict__ wtimg, unsigned* __restrict__ pw1img,
    int* __restrict__ gstart){
  int idx = blockIdx.x*256 + threadIdx.x;
  if (idx < 3*256*64){
    int l  = idx / (256*64);
    int r  = idx - l*(256*64);
    int n  = r >> 6;
    int kp = r & 63;
    const float* Wp = (n < 128) ? (gWsrc + (size_t)l*HID*HID)
                                : (gWdst + (size_t)l*HID*HID - 128);
    float w0 = Wp[(2*kp)*HID + n];
    float w1 = Wp[(2*kp+1)*HID + n];
    int byt = (n*256 + kp*4) ^ ((n&7)<<4);
    *(unsigned*)((char*)(wtimg + (size_t)l*16384) + byt) = pack2(w0, w1);
  } else if (idx < WPREP_T){
    int r = idx - 3*256*64;
    int n  = r >> 6;
    int kp = r & 63;
    float w0 = pW1[(2*kp)*HID + n];
    float w1 = pW1[(2*kp+1)*HID + n];
    int byt = (n*256 + kp*4) ^ ((n&7)<<4);
    *(unsigned*)((char*)pw1img + byt) = pack2(w0, w1);
  } else {
    int n = idx - WPREP_T;
    if (n >= Nn) return;
    int bc = batch[n];
    int bp = (n==0) ? -1 : batch[n-1];
    for (int b = bp+1; b <= bc; ++b) gstart[b] = n;
    if (n == Nn-1){ for (int b = bc+1; b <= Bb; ++b) gstart[b] = Nn; }
  }
}

// ---------------- encoder: hbu = bf16(LN(ReLU(x @ W + b))) ----------------
__global__ __launch_bounds__(256) void k_encoder(
    const float* __restrict__ x, const float* __restrict__ W, const float* __restrict__ b,
    const float* __restrict__ g, const float* __restrict__ bbv,
    unsigned* __restrict__ hbu){
  int wv = (blockIdx.x*blockDim.x + threadIdx.x) >> 6;
  if (wv >= Nn) return;
  int lane = threadIdx.x & 63;
  int d0 = 2*lane, d1 = d0+1;
  float y0 = b[d0], y1 = b[d1];
  #pragma unroll
  for (int i=0;i<NFd;++i){
    float xv = x[wv*NFd + i];
    y0 = fmaf(xv, W[i*HID + d0], y0);
    y1 = fmaf(xv, W[i*HID + d1], y1);
  }
  y0 = fmaxf(y0, 0.f); y1 = fmaxf(y1, 0.f);
  float mu = wred_sum(y0+y1) * (1.f/HID);
  float c0 = y0-mu, c1 = y1-mu;
  float var = wred_sum(c0*c0 + c1*c1) * (1.f/HID);
  float rs = rsqrtf(var + EPS);
  float v0 = g[d0]*c0*rs + bbv[d0];
  float v1 = g[d1]*c1*rs + bbv[d1];
  hbu[(size_t)wv*64 + lane] = pack2(v0, v1);
}

// ---------------- degree count + edge_attr mean (one edge per thread) ------
__global__ void k_deg(const int* __restrict__ ei, const float* __restrict__ ea,
    int* __restrict__ deg, float* __restrict__ eam){
  int e = blockIdx.x*blockDim.x + threadIdx.x;
  float a0 = 0.f, a1 = 0.f;
  if (e < Ee){
    atomicAdd(&deg[ei[Ee + e]], 1);
    float2 v = ((const float2*)ea)[e];
    a0 = v.x; a1 = v.y;
  }
  a0 = wred_sum(a0); a1 = wred_sum(a1);
  if ((threadIdx.x & 63)==0 && a0 != 0.f){
    atomicAdd(&eam[0], a0*(1.f/Ee));
    atomicAdd(&eam[1], a1*(1.f/Ee));
  }
}

// ---------------- scan (deg+1 folds in the self-loop) ----------------
__global__ __launch_bounds__(1024) void k_scan(const int* __restrict__ deg,
    int* __restrict__ offs, int* __restrict__ cursor){
  __shared__ int wsum[16];
  __shared__ int tot_s;
  __shared__ int carry_s;
  int t = threadIdx.x, lane = t & 63, wid = t >> 6;
  if (t==0) carry_s = 0;
  __syncthreads();
  for (int base=0; base<Nn; base += 4096){
    int i0 = base + t*4;
    int v0=0,v1=0,v2=0,v3=0;
    if (i0+3 < Nn){
      int4 qv = *(const int4*)(deg + i0);
      v0=qv.x+1; v1=qv.y+1; v2=qv.z+1; v3=qv.w+1;
    } else {
      if (i0   < Nn) v0 = deg[i0]+1;
      if (i0+1 < Nn) v1 = deg[i0+1]+1;
      if (i0+2 < Nn) v2 = deg[i0+2]+1;
      if (i0+3 < Nn) v3 = deg[i0+3]+1;
    }
    int tot = v0+v1+v2+v3;
    int x = tot;
    #pragma unroll
    for (int o=1;o<64;o<<=1){ int u = __shfl_up(x, o, 64); if (lane >= o) x += u; }
    if (lane==63) wsum[wid] = x;
    __syncthreads();
    if (t==0){ int s=0; for (int k=0;k<16;++k){ int tv=wsum[k]; wsum[k]=s; s+=tv; } tot_s = s; }
    __syncthreads();
    int excl = carry_s + wsum[wid] + (x - tot);
    int p0 = excl, p1 = excl+v0, p2 = p1+v1, p3 = p2+v2;
    if (i0+3 < Nn){
      *(int4*)(offs + i0)   = make_int4(p0,p1,p2,p3);
      *(int4*)(cursor + i0) = make_int4(p0,p1,p2,p3);
    } else {
      if (i0   < Nn){ offs[i0]  =p0; cursor[i0]  =p0; }
      if (i0+1 < Nn){ offs[i0+1]=p1; cursor[i0+1]=p1; }
      if (i0+2 < Nn){ offs[i0+2]=p2; cursor[i0+2]=p2; }
      if (i0+3 < Nn){ offs[i0+3]=p3; cursor[i0+3]=p3; }
    }
    __syncthreads();
    if (t==0) carry_s += tot_s;
    __syncthreads();
  }
  if (t==0) offs[Nn] = carry_s;
}

// scatter combined 16B edge records + 16-entry zero pad past E2
__global__ void k_scatter(const int* __restrict__ ei, const float* __restrict__ ea,
    const float* __restrict__ eam, int* __restrict__ cursor,
    int4* __restrict__ ecomb){
  int e = blockIdx.x*blockDim.x + threadIdx.x;
  if (e >= E2 + 16) return;
  if (e >= E2){
    ecomb[e] = make_int4(0, 0, 0, 0);
    return;
  }
  int s, d; float a0, a1;
  if (e < Ee){
    s = ei[e]; d = ei[Ee + e];
    float2 v = ((const float2*)ea)[e];
    a0 = v.x; a1 = v.y;
  } else {
    s = d = e - Ee; a0 = eam[0]; a1 = eam[1];
  }
  int pos = atomicAdd(&cursor[d], 1);
  ecomb[pos] = make_int4(s, __float_as_int(a0), __float_as_int(a1), 0);
}

// ---------------- MFMA dual GEMM: hs(bf16)=h@Wsrc, hd(f32)=h@Wdst ----------
__global__ __launch_bounds__(256) void k_dualgemm(
    const unsigned* __restrict__ hbu, const unsigned* __restrict__ wtimg,
    unsigned* __restrict__ hsb, float* __restrict__ hd){
  __shared__ unsigned wt[16384];  // 64 KiB
  for (int i = threadIdx.x; i < 4096; i += 256)
    ((uint4*)wt)[i] = ((const uint4*)wtimg)[i];
  __syncthreads();
  int wid = threadIdx.x >> 6, lane = threadIdx.x & 63;
  int q = lane >> 4, c = lane & 15;
  const unsigned short* hb = (const unsigned short*)hbu;
  for (int pr = blockIdx.x*4 + wid; pr < NPAIR; pr += gridDim.x*4){
    int p0 = 2*pr, p1 = 2*pr + 1;
    bool v1 = (p1 < NSTRIP);
    int node0 = p0*16 + c;
    int node1 = v1 ? (p1*16 + c) : node0;
    short8 bf0[4], bf1[4];
    const unsigned short* hp0 = hb + (size_t)node0*HID + q*8;
    const unsigned short* hp1 = hb + (size_t)node1*HID + q*8;
    #pragma unroll
    for (int s=0;s<4;++s){
      bf0[s] = *(const short8*)(hp0 + s*32);
      bf1[s] = *(const short8*)(hp1 + s*32);
    }
    #pragma unroll 4
    for (int t=0;t<16;++t){
      float4v ac0 = {0.f,0.f,0.f,0.f}, ac1 = {0.f,0.f,0.f,0.f};
      #pragma unroll
      for (int s=0;s<4;++s){
        int row = t*16 + c;
        int byt = (row*256 + s*64 + q*16) ^ ((row&7)<<4);
        short8 af = *(const short8*)((const char*)wt + byt);
        ac0 = MFMA16(af, bf0[s], ac0);
        ac1 = MFMA16(af, bf1[s], ac1);
      }
      if (t < 8){
        int co = t*8 + q*2;
        *(uint2*)(hsb + (size_t)node0*64 + co) =
            make_uint2(pack2(ac0[0],ac0[1]), pack2(ac0[2],ac0[3]));
        if (v1) *(uint2*)(hsb + (size_t)node1*64 + co) =
            make_uint2(pack2(ac1[0],ac1[1]), pack2(ac1[2],ac1[3]));
      } else {
        int dd = (t-8)*16 + q*4;
        *(float4*)(hd + (size_t)node0*HID + dd) = make_float4(ac0[0],ac0[1],ac0[2],ac0[3]);
        if (v1) *(float4*)(hd + (size_t)node1*HID + dd) = make_float4(ac1[0],ac1[1],ac1[2],ac1[3]);
      }
    }
  }
}

// ---------------- GATv2 edge aggregation: 4 edges/wave, 16 lanes/edge -------
__global__ __launch_bounds__(256) void k_edge(const unsigned* __restrict__ hsb,
    float* __restrict__ hdio, const unsigned* __restrict__ hbu,
    const int4* __restrict__ ecomb,
    const int* __restrict__ offs, const float* __restrict__ We,
    const float* __restrict__ att, const float* __restrict__ bias){
  int bid = xcd_swizzle(blockIdx.x, gridDim.x);
  int n = (bid*256 + (int)threadIdx.x) >> 6;
  if (n >= Nn) return;
  int lane = threadIdx.x & 63;
  int row = lane >> 4;      // edge slot 0..3
  int c   = lane & 15;      // dim group
  int d0  = 8*c;            // dims d0..d0+7, head = c>>2
  float we0[8], we1[8], at[8], xr[8];
  #pragma unroll
  for (int j=0;j<8;++j){
    we0[j] = We[d0+j];
    we1[j] = We[HID+d0+j];
    at[j]  = att[d0+j] * LOG2E;
  }
  *(float4*)(xr)   = *(const float4*)(hdio + (size_t)n*HID + d0);
  *(float4*)(xr+4) = *(const float4*)(hdio + (size_t)n*HID + d0 + 4);
  int e0 = offs[n], e1 = offs[n+1];
  float m = 0.f, ssum = 0.f;
  float acc[8];
  #pragma unroll
  for (int j=0;j<8;++j) acc[j] = 0.f;

  // 1-deep unconditional prefetch; ecomb padded by 16 entries past E2
  int4  rC = ecomb[e0 + row];
  uint4 xC = *(const uint4*)(hsb + ((size_t)(unsigned)rC.x<<6) + 4*c);
  bool  vC = (e0 + row) < e1;
  for (int e = e0; e < e1; e += 4){
    int en = e + 4 + row;
    int4  rN = ecomb[en];
    uint4 xN = *(const uint4*)(hsb + ((size_t)(unsigned)rN.x<<6) + 4*c);
    bool  vN = en < e1;
    float xl[8];
    xl[0]=bf_lo(xC.x); xl[1]=bf_hi(xC.x); xl[2]=bf_lo(xC.y); xl[3]=bf_hi(xC.y);
    xl[4]=bf_lo(xC.z); xl[5]=bf_hi(xC.z); xl[6]=bf_lo(xC.w); xl[7]=bf_hi(xC.w);
    float eCx = __int_as_float(rC.y), eCy = __int_as_float(rC.z);
    float dot = 0.f;
    #pragma unroll
    for (int j=0;j<8;++j){
      float z = fmaf(eCy, we1[j], fmaf(eCx, we0[j], xl[j] + xr[j]));
      z = fmaxf(z, SLOPE*z);
      dot = fmaf(z, at[j], dot);
    }
    float sc = red4_quad(dot);          // per-(edge-slot, head) score (log2 units)
    if (e == e0) m = __shfl(sc, lane & 15, 64);  // slot-0's score per head
    float p = exp2f(sc - m);
    p = vC ? p : 0.f;
    ssum += p;
    #pragma unroll
    for (int j=0;j<8;++j) acc[j] = fmaf(p, xl[j], acc[j]);
    rC=rN; xC=xN; vC=vN;
  }
  #pragma unroll
  for (int j=0;j<8;++j){
    acc[j] += __shfl_xor(acc[j], 16, 64);
    acc[j] += __shfl_xor(acc[j], 32, 64);
  }
  ssum += __shfl_xor(ssum, 16, 64);
  ssum += __shfl_xor(ssum, 32, 64);
  if (row == 0){
    float inv = 1.f/ssum;
    uint4 hu = *(const uint4*)(hbu + ((size_t)n<<6) + 4*c);
    float hr[8];
    hr[0]=bf_lo(hu.x); hr[1]=bf_hi(hu.x); hr[2]=bf_lo(hu.y); hr[3]=bf_hi(hu.y);
    hr[4]=bf_lo(hu.z); hr[5]=bf_hi(hu.z); hr[6]=bf_lo(hu.w); hr[7]=bf_hi(hu.w);
    float o[8];
    #pragma unroll
    for (int j=0;j<8;++j) o[j] = fmaf(acc[j], inv, bias[d0+j] + hr[j]);
    *(float4*)(hdio + (size_t)n*HID + d0)     = make_float4(o[0],o[1],o[2],o[3]);
    *(float4*)(hdio + (size_t)n*HID + d0 + 4) = make_float4(o[4],o[5],o[6],o[7]);
  }
}

// ---------------- GraphNorm reduce: per-(graph,dim) sum & sumsq ----------------
__global__ __launch_bounds__(128) void k_gn_reduce(const float* __restrict__ out,
    const int* __restrict__ gstart, float* __restrict__ gsum_, float* __restrict__ gsq_){
  int b = blockIdx.x >> 4, sub = blockIdx.x & 15;
  int ns = gstart[b], ne = gstart[b+1];
  int d = threadIdx.x;
  float s = 0.f, qq = 0.f;
  for (int n = ns + sub; n < ne; n += 16){
    float v = out[(size_t)n*HID + d];
    s += v; qq = fmaf(v, v, qq);
  }
  atomicAdd(&gsum_[b*HID + d], s);
  atomicAdd(&gsq_[b*HID + d], qq);
}

// ---------------- GraphNorm apply + ELU: wave per node ----------------
__global__ __launch_bounds__(256) void k_gn_apply(const float* __restrict__ out,
    const float* __restrict__ gsum_, const float* __restrict__ gsq_,
    const int* __restrict__ gstart, const int* __restrict__ batch,
    const float* __restrict__ gw, const float* __restrict__ gb,
    const float* __restrict__ gs,
    unsigned* __restrict__ hbu, float* __restrict__ emb){
  int n = (blockIdx.x*blockDim.x + threadIdx.x) >> 6;
  if (n >= Nn) return;
  int lane = threadIdx.x & 63;
  int b = batch[n];
  float icnt = 1.f / fmaxf((float)(gstart[b+1]-gstart[b]), 1.f);
  int d0 = 2*lane, d1 = d0+1;
  float2 x = *(const float2*)(out + (size_t)n*HID + d0);
  float mean0 = gsum_[b*HID+d0]*icnt, mean1 = gsum_[b*HID+d1]*icnt;
  float ms0 = mean0*gs[d0], ms1 = mean1*gs[d1];
  float var0 = gsq_[b*HID+d0]*icnt - ms0*(2.f*mean0 - ms0);
  float var1 = gsq_[b*HID+d1]*icnt - ms1*(2.f*mean1 - ms1);
  float rs0 = rsqrtf(fmaxf(var0, 0.f) + EPS);
  float rs1 = rsqrtf(fmaxf(var1, 0.f) + EPS);
  float y0 = gw[d0]*(x.x - ms0)*rs0 + gb[d0];
  float y1 = gw[d1]*(x.y - ms1)*rs1 + gb[d1];
  y0 = (y0 > 0.f) ? y0 : (__expf(y0) - 1.f);
  y1 = (y1 > 0.f) ? y1 : (__expf(y1) - 1.f);
  hbu[(size_t)n*64 + lane] = pack2(y0, y1);
  if (emb) *(float2*)(emb + (size_t)n*HID + d0) = make_float2(y0, y1);
}

// ---------------- pooling scores via MFMA + global max ----------------
__global__ __launch_bounds__(256) void k_pool_score(
    const unsigned* __restrict__ hbu, const unsigned* __restrict__ pw1img,
    const float* __restrict__ b1, const float* __restrict__ W2,
    float* __restrict__ score, unsigned* __restrict__ mkey){
  __shared__ unsigned wt[8192];  // 32 KiB, pre-swizzled image
  __shared__ float b1l[HID], w2l[HID];
  for (int i = threadIdx.x; i < 2048; i += 256)
    ((uint4*)wt)[i] = ((const uint4*)pw1img)[i];
  if (threadIdx.x < HID){ b1l[threadIdx.x] = b1[threadIdx.x]; w2l[threadIdx.x] = W2[threadIdx.x]; }
  __syncthreads();
  int wid = threadIdx.x >> 6, lane = threadIdx.x & 63;
  int q = lane >> 4, c = lane & 15;
  const unsigned short* hb = (const unsigned short*)hbu;
  float bmax = -1e30f;
  for (int p = blockIdx.x*4 + wid; p < NSTRIP; p += gridDim.x*4){
    int node = p*16 + c;
    short8 bf[4];
    const unsigned short* hp = hb + (size_t)node*HID + q*8;
    #pragma unroll
    for (int s=0;s<4;++s) bf[s] = *(const short8*)(hp + s*32);
    float part = 0.f;
    #pragma unroll
    for (int t=0;t<8;++t){
      float4v ac = {0.f,0.f,0.f,0.f};
      #pragma unroll
      for (int s=0;s<4;++s){
        int row = t*16 + c;
        int byt = (row*256 + s*64 + q*16) ^ ((row&7)<<4);
        ac = MFMA16(*(const short8*)((const char*)wt + byt), bf[s], ac);
      }
      int dim = t*16 + q*4;
      #pragma unroll
      for (int r=0;r<4;++r)
        part += tanh_fast(ac[r] + b1l[dim+r]) * w2l[dim+r];
    }
    part += __shfl_xor(part, 16, 64);
    part += __shfl_xor(part, 32, 64);
    if (q==0) score[node] = part;
    bmax = fmaxf(bmax, part);
  }
  #pragma unroll
  for (int o=32;o;o>>=1) bmax = fmaxf(bmax, __shfl_xor(bmax, o, 64));
  if (lane==0) atomicMax(mkey, fkey(bmax));
}

// ---------------- pooled accumulation per (graph,sub) ----------------
__global__ __launch_bounds__(128) void k_pool_reduce(const unsigned* __restrict__ hbu,
    const float* __restrict__ score, const unsigned* __restrict__ mkey,
    const int* __restrict__ gstart, float* __restrict__ gsum, float* __restrict__ total){
  int b = blockIdx.x >> 4, sub = blockIdx.x & 15;
  int ns = gstart[b], ne = gstart[b+1];
  float mx = fkeyinv(*mkey);
  int d = threadIdx.x;
  float acc = 0.f, es = 0.f;
  for (int n = ns + sub; n < ne; n += 16){
    float ev = __expf(score[n] - mx);
    unsigned u = hbu[(size_t)n*64 + (d>>1)];
    float hv = (d & 1) ? bf_hi(u) : bf_lo(u);
    acc = fmaf(ev, hv, acc);
    if (d==0) es += ev;
  }
  atomicAdd(&gsum[b*HID + d], acc);
  if (d==0) atomicAdd(total, es);
}

// ---------------- output mapper: one wave per graph ----------------
__global__ __launch_bounds__(64) void k_mapper(const float* __restrict__ gsum,
    const float* __restrict__ total,
    const float* __restrict__ W1, const float* __restrict__ b1,
    const float* __restrict__ g,  const float* __restrict__ bbv,
    const float* __restrict__ W2, const float* __restrict__ b2v,
    float* __restrict__ out0){
  int b = blockIdx.x, lane = threadIdx.x;
  float inv = 1.f/(*total);
  int d0 = 2*lane, d1 = d0+1;
  float gv0 = gsum[b*HID + d0]*inv, gv1 = gsum[b*HID + d1]*inv;
  float a0 = b1[d0], a1 = b1[d1];
  for (int i=0;i<HID;++i){
    float hv = lane_bcast((i&1) ? gv1 : gv0, i>>1);
    a0 = fmaf(hv, W1[i*HID + d0], a0);
    a1 = fmaf(hv, W1[i*HID + d1], a1);
  }
  a0 = fmaxf(a0, 0.f); a1 = fmaxf(a1, 0.f);
  float mu = wred_sum(a0+a1) * (1.f/HID);
  float c0 = a0-mu, c1 = a1-mu;
  float var = wred_sum(c0*c0 + c1*c1) * (1.f/HID);
  float rs = rsqrtf(var + EPS);
  float l0 = g[d0]*c0*rs + bbv[d0];
  float l1 = g[d1]*c1*rs + bbv[d1];
  float acc = b2v[lane];
  for (int j=0;j<HID;++j){
    float lv = lane_bcast((j&1) ? l1 : l0, j>>1);
    acc = fmaf(lv, W2[j*OUTD + lane], acc);
  }
  out0[b*OUTD + lane] = acc;
}

// =====================================================================
extern "C" void kernel_launch(void* const* d_in, const int* in_sizes, int n_in,
                              void* d_out, int out_size, void* d_ws, size_t ws_size,
                              hipStream_t stream){
  const float* x     = (const float*)d_in[0];
  const int*   ei    = (const int*)  d_in[1];
  const float* ea    = (const float*)d_in[2];
  const int*   batch = (const int*)  d_in[3];
  const float* encW  = (const float*)d_in[4];
  const float* encb  = (const float*)d_in[5];
  const float* encg  = (const float*)d_in[6];
  const float* encbb = (const float*)d_in[7];
  const float* gWsrc = (const float*)d_in[8];
  const float* gWdst = (const float*)d_in[9];
  const float* gWe   = (const float*)d_in[10];
  const float* gatt  = (const float*)d_in[11];
  const float* gbias = (const float*)d_in[12];
  const float* gnw   = (const float*)d_in[13];
  const float* gnb   = (const float*)d_in[14];
  const float* gns   = (const float*)d_in[15];
  const float* pW1   = (const float*)d_in[16];
  const float* pb1   = (const float*)d_in[17];
  const float* pW2   = (const float*)d_in[18];
  const float* mW1   = (const float*)d_in[19];
  const float* mb1   = (const float*)d_in[20];
  const float* mg    = (const float*)d_in[21];
  const float* mbb   = (const float*)d_in[22];
  const float* mW2   = (const float*)d_in[23];
  const float* mb2   = (const float*)d_in[24];

  char* w = (char*)d_ws;
  size_t off = 0;
  auto alloc = [&](size_t bytes)->char*{
    char* p = w + off;
    off += (bytes + 255) & ~(size_t)255;
    return p;
  };
  unsigned* hbu    = (unsigned*)alloc((size_t)Nn*64*4);    // bf16-packed h
  unsigned* hsb    = (unsigned*)alloc((size_t)Nn*64*4);    // bf16-packed hs
  float*    hd     = (float*)   alloc((size_t)Nn*HID*4);   // hd, then GAT 'out' in place
  int4*     ecomb  = (int4*)    alloc((size_t)(E2+16)*16); // {src, ea0, ea1, 0}
  int*      offs   = (int*)     alloc((size_t)(Nn+1)*4);
  int*      cursor = (int*)     alloc((size_t)Nn*4);
  int*      deg    = (int*)     alloc((size_t)Nn*4);
  int*      gstart = (int*)     alloc((size_t)(Bb+1)*4);
  float*    score  = (float*)   alloc((size_t)Nn*4);
  // zero-region: gsum | 3 layers × (gnsum|gnsq) — one memset
  float*    gsum   = (float*)   alloc((size_t)Bb*HID*4 * 7);
  float*    gnbase = gsum + Bb*HID;
  unsigned* wtimg  = (unsigned*)alloc((size_t)3*16384*4);  // pre-swizzled W_T images
  unsigned* pw1img = (unsigned*)alloc((size_t)8192*4);
  float*    scal   = (float*)   alloc(256); // [0]=eam0 [1]=eam1 [2]=total [3]=mkey
  float*    eam   = scal;
  float*    total = scal + 2;
  unsigned* mkey  = (unsigned*)(scal + 3);

  float* out_graph = (float*)d_out;
  float* out_node  = (float*)d_out + (size_t)Bb*OUTD;

  hipMemsetAsync(deg,  0, (size_t)Nn*4, stream);
  hipMemsetAsync(scal, 0, 256, stream);
  hipMemsetAsync(gsum, 0, (size_t)Bb*HID*4 * 7, stream);

  k_prep<<<(WPREP_T + Nn + 255)/256, 256, 0, stream>>>(gWsrc, gWdst, pW1, batch,
                                                       wtimg, pw1img, gstart);
  k_encoder<<<Nn/4, 256, 0, stream>>>(x, encW, encb, encg, encbb, hbu);
  k_deg<<<(Ee+255)/256, 256, 0, stream>>>(ei, ea, deg, eam);
  k_scan<<<1, 1024, 0, stream>>>(deg, offs, cursor);
  k_scatter<<<(E2+16+255)/256, 256, 0, stream>>>(ei, ea, eam, cursor, ecomb);

  for (int l = 0; l < 3; ++l){
    float* gnsum_l = gnbase + (size_t)l*2*Bb*HID;
    float* gnsq_l  = gnsum_l + Bb*HID;
    k_dualgemm<<<392, 256, 0, stream>>>(hbu, wtimg + (size_t)l*16384, hsb, hd);
    k_edge<<<Nn/4, 256, 0, stream>>>(hsb, hd, hbu, ecomb, offs,
                                     gWe + (size_t)l*2*HID,
                                     gatt + (size_t)l*4*32,
                                     gbias + (size_t)l*HID);
    k_gn_reduce<<<Bb*16, 128, 0, stream>>>(hd, gstart, gnsum_l, gnsq_l);
    k_gn_apply<<<Nn/4, 256, 0, stream>>>(hd, gnsum_l, gnsq_l, gstart, batch,
                                         gnw + (size_t)l*HID, gnb + (size_t)l*HID,
                                         gns + (size_t)l*HID, hbu,
                                         (l==2) ? out_node : (float*)nullptr);
  }

  k_pool_score<<<256, 256, 0, stream>>>(hbu, pw1img, pb1, pW2, score, mkey);
  k_pool_reduce<<<Bb*16, 128, 0, stream>>>(hbu, score, mkey, gstart, gsum, total);
  k_mapper<<<Bb, 64, 0, stream>>>(gsum, total, mW1, mb1, mg, mbb, mW2, mb2, out_graph);
}

// Round 15
// 538.106 us; speedup vs baseline: 1.4584x; 1.4584x over previous
//
#include <hip/hip_runtime.h>
#include <hip/hip_bf16.h>

typedef __hip_bfloat16 bf16;
typedef __attribute__((ext_vector_type(8))) short short8;
typedef __attribute__((ext_vector_type(4))) float float4v;

#define Nn   50000
#define Ee   800000
#define E2   850000
#define Bb   128
#define NFd  7
#define HID  128
#define OUTD 64
#define EPS  1e-5f
#define SLOPE 0.2f
#define LOG2E 1.4426950408889634f
#define NSTRIP 3125          // Nn/16
#define NPAIR  1563          // ceil(NSTRIP/2)

#define MFMA16(a,b,c) __builtin_amdgcn_mfma_f32_16x16x32_bf16(a,b,c,0,0,0)

__device__ __forceinline__ float lane_bcast(float v, int l){
  return __int_as_float(__builtin_amdgcn_readlane(__float_as_int(v), l));
}
__device__ __forceinline__ float wred_sum(float v){
  #pragma unroll
  for (int o=32;o;o>>=1) v += __shfl_xor(v, o, 64);
  return v;
}
// compiler-managed DPP helpers (hazard-safe)
#define UPD_DPP(x, ctrl) \
  __int_as_float(__builtin_amdgcn_update_dpp(0, __float_as_int(x), (ctrl), 0xf, 0xf, false))
// sum over each 4-lane quad (quad == attention head group)
__device__ __forceinline__ float red4_quad(float x){
  x = x + UPD_DPP(x, 0xB1);  // quad_perm [1,0,3,2]
  x = x + UPD_DPP(x, 0x4E);  // quad_perm [2,3,0,1]
  return x;
}
__device__ __forceinline__ unsigned fkey(float f){
  unsigned u = __float_as_uint(f);
  return (u & 0x80000000u) ? ~u : (u | 0x80000000u);
}
__device__ __forceinline__ float fkeyinv(unsigned k){
  unsigned u = (k & 0x80000000u) ? (k ^ 0x80000000u) : ~k;
  return __uint_as_float(u);
}
__device__ __forceinline__ float tanh_fast(float x){
  float e = __expf(fminf(fmaxf(2.f*x, -30.f), 30.f));
  return (e-1.f)/(e+1.f);
}
__device__ __forceinline__ float bf_lo(unsigned u){ return __uint_as_float(u<<16); }
__device__ __forceinline__ float bf_hi(unsigned u){ return __uint_as_float(u & 0xffff0000u); }
__device__ __forceinline__ unsigned short f2bs(float f){
  bf16 h = __float2bfloat16(f);
  return *reinterpret_cast<unsigned short*>(&h);
}
__device__ __forceinline__ unsigned pack2(float a, float b){
  return (unsigned)f2bs(a) | ((unsigned)f2bs(b) << 16);
}
// bijective XCD swizzle (m204): contiguous chunk per XCD
__device__ __forceinline__ int xcd_swizzle(int bid, int nwg){
  int q = nwg >> 3, r = nwg & 7;
  int x = bid & 7, i = bid >> 3;
  return (x < r ? x*(q+1) : r*(q+1) + (x-r)*q) + i;
}

// ---------------- weight prep: pre-swizzled bf16 LDS images ----------------
__global__ __launch_bounds__(256) void k_wprep(
    const float* __restrict__ gWsrc, const float* __restrict__ gWdst,
    const float* __restrict__ pW1,
    unsigned* __restrict__ wtimg, unsigned* __restrict__ pw1img){
  int idx = blockIdx.x*256 + threadIdx.x;
  if (idx < 3*256*64){
    int l  = idx / (256*64);
    int r  = idx - l*(256*64);
    int n  = r >> 6;
    int kp = r & 63;
    const float* Wp = (n < 128) ? (gWsrc + (size_t)l*HID*HID)
                                : (gWdst + (size_t)l*HID*HID - 128);
    float w0 = Wp[(2*kp)*HID + n];
    float w1 = Wp[(2*kp+1)*HID + n];
    int byt = (n*256 + kp*4) ^ ((n&7)<<4);
    *(unsigned*)((char*)(wtimg + (size_t)l*16384) + byt) = pack2(w0, w1);
  } else {
    int r = idx - 3*256*64;
    if (r < 128*64){
      int n  = r >> 6;
      int kp = r & 63;
      float w0 = pW1[(2*kp)*HID + n];
      float w1 = pW1[(2*kp+1)*HID + n];
      int byt = (n*256 + kp*4) ^ ((n&7)<<4);
      *(unsigned*)((char*)pw1img + byt) = pack2(w0, w1);
    }
  }
}

// ---------------- encoder: hbu = bf16(LN(ReLU(x @ W + b))) ----------------
__global__ __launch_bounds__(256) void k_encoder(
    const float* __restrict__ x, const float* __restrict__ W, const float* __restrict__ b,
    const float* __restrict__ g, const float* __restrict__ bbv,
    unsigned* __restrict__ hbu){
  int wv = (blockIdx.x*blockDim.x + threadIdx.x) >> 6;
  if (wv >= Nn) return;
  int lane = threadIdx.x & 63;
  int d0 = 2*lane, d1 = d0+1;
  float y0 = b[d0], y1 = b[d1];
  #pragma unroll
  for (int i=0;i<NFd;++i){
    float xv = x[wv*NFd + i];
    y0 = fmaf(xv, W[i*HID + d0], y0);
    y1 = fmaf(xv, W[i*HID + d1], y1);
  }
  y0 = fmaxf(y0, 0.f); y1 = fmaxf(y1, 0.f);
  float mu = wred_sum(y0+y1) * (1.f/HID);
  float c0 = y0-mu, c1 = y1-mu;
  float var = wred_sum(c0*c0 + c1*c1) * (1.f/HID);
  float rs = rsqrtf(var + EPS);
  float v0 = g[d0]*c0*rs + bbv[d0];
  float v1 = g[d1]*c1*rs + bbv[d1];
  hbu[(size_t)wv*64 + lane] = pack2(v0, v1);
}

// ---------------- mean of edge_attr (pure reduce, 256 blocks) --------------
__global__ void k_ea_mean(const float* __restrict__ ea, float* __restrict__ eam){
  int tid = blockIdx.x*blockDim.x + threadIdx.x;
  const float2* ea2 = (const float2*)ea;
  float a0=0.f, a1=0.f;
  for (int e=tid; e<Ee; e += gridDim.x*blockDim.x){
    float2 v = ea2[e];
    a0 += v.x; a1 += v.y;
  }
  a0 = wred_sum(a0); a1 = wred_sum(a1);
  if ((threadIdx.x & 63)==0){
    atomicAdd(&eam[0], a0*(1.f/Ee));
    atomicAdd(&eam[1], a1*(1.f/Ee));
  }
}

// ---------------- degree count: one atomic per real edge -------------------
__global__ void k_deg(const int* __restrict__ ei, int* __restrict__ deg){
  int e = blockIdx.x*blockDim.x + threadIdx.x;
  if (e >= Ee) return;
  atomicAdd(&deg[ei[Ee + e]], 1);
}

// ---------------- scan (deg+1 folds in the self-loop) ----------------
__global__ __launch_bounds__(1024) void k_scan(const int* __restrict__ deg,
    int* __restrict__ offs, int* __restrict__ cursor){
  __shared__ int wsum[16];
  __shared__ int tot_s;
  __shared__ int carry_s;
  int t = threadIdx.x, lane = t & 63, wid = t >> 6;
  if (t==0) carry_s = 0;
  __syncthreads();
  for (int base=0; base<Nn; base += 4096){
    int i0 = base + t*4;
    int v0=0,v1=0,v2=0,v3=0;
    if (i0+3 < Nn){
      int4 qv = *(const int4*)(deg + i0);
      v0=qv.x+1; v1=qv.y+1; v2=qv.z+1; v3=qv.w+1;
    } else {
      if (i0   < Nn) v0 = deg[i0]+1;
      if (i0+1 < Nn) v1 = deg[i0+1]+1;
      if (i0+2 < Nn) v2 = deg[i0+2]+1;
      if (i0+3 < Nn) v3 = deg[i0+3]+1;
    }
    int tot = v0+v1+v2+v3;
    int x = tot;
    #pragma unroll
    for (int o=1;o<64;o<<=1){ int u = __shfl_up(x, o, 64); if (lane >= o) x += u; }
    if (lane==63) wsum[wid] = x;
    __syncthreads();
    if (t==0){ int s=0; for (int k=0;k<16;++k){ int tv=wsum[k]; wsum[k]=s; s+=tv; } tot_s = s; }
    __syncthreads();
    int excl = carry_s + wsum[wid] + (x - tot);
    int p0 = excl, p1 = excl+v0, p2 = p1+v1, p3 = p2+v2;
    if (i0+3 < Nn){
      *(int4*)(offs + i0)   = make_int4(p0,p1,p2,p3);
      *(int4*)(cursor + i0) = make_int4(p0,p1,p2,p3);
    } else {
      if (i0   < Nn){ offs[i0]  =p0; cursor[i0]  =p0; }
      if (i0+1 < Nn){ offs[i0+1]=p1; cursor[i0+1]=p1; }
      if (i0+2 < Nn){ offs[i0+2]=p2; cursor[i0+2]=p2; }
      if (i0+3 < Nn){ offs[i0+3]=p3; cursor[i0+3]=p3; }
    }
    __syncthreads();
    if (t==0) carry_s += tot_s;
    __syncthreads();
  }
  if (t==0) offs[Nn] = carry_s;
}

// scatter combined 16B edge records + 16-entry zero pad past E2
__global__ void k_scatter(const int* __restrict__ ei, const float* __restrict__ ea,
    const float* __restrict__ eam, int* __restrict__ cursor,
    int4* __restrict__ ecomb){
  int e = blockIdx.x*blockDim.x + threadIdx.x;
  if (e >= E2 + 16) return;
  if (e >= E2){
    ecomb[e] = make_int4(0, 0, 0, 0);
    return;
  }
  int s, d; float a0, a1;
  if (e < Ee){
    s = ei[e]; d = ei[Ee + e];
    float2 v = ((const float2*)ea)[e];
    a0 = v.x; a1 = v.y;
  } else {
    s = d = e - Ee; a0 = eam[0]; a1 = eam[1];
  }
  int pos = atomicAdd(&cursor[d], 1);
  ecomb[pos] = make_int4(s, __float_as_int(a0), __float_as_int(a1), 0);
}

// ---------------- per-graph node ranges (batch is sorted) ----------------
__global__ void k_gstart(const int* __restrict__ batch, int* __restrict__ gstart){
  int n = blockIdx.x*blockDim.x + threadIdx.x;
  if (n >= Nn) return;
  int bc = batch[n];
  int bp = (n==0) ? -1 : batch[n-1];
  for (int b = bp+1; b <= bc; ++b) gstart[b] = n;
  if (n == Nn-1){ for (int b = bc+1; b <= Bb; ++b) gstart[b] = Nn; }
}

// ---------------- MFMA dual GEMM: hs(bf16)=h@Wsrc, hd(f32)=h@Wdst ----------
__global__ __launch_bounds__(256) void k_dualgemm(
    const unsigned* __restrict__ hbu, const unsigned* __restrict__ wtimg,
    unsigned* __restrict__ hsb, float* __restrict__ hd){
  __shared__ unsigned wt[16384];  // 64 KiB
  for (int i = threadIdx.x; i < 4096; i += 256)
    ((uint4*)wt)[i] = ((const uint4*)wtimg)[i];
  __syncthreads();
  int wid = threadIdx.x >> 6, lane = threadIdx.x & 63;
  int q = lane >> 4, c = lane & 15;
  const unsigned short* hb = (const unsigned short*)hbu;
  for (int pr = blockIdx.x*4 + wid; pr < NPAIR; pr += gridDim.x*4){
    int p0 = 2*pr, p1 = 2*pr + 1;
    bool v1 = (p1 < NSTRIP);
    int node0 = p0*16 + c;
    int node1 = v1 ? (p1*16 + c) : node0;
    short8 bf0[4], bf1[4];
    const unsigned short* hp0 = hb + (size_t)node0*HID + q*8;
    const unsigned short* hp1 = hb + (size_t)node1*HID + q*8;
    #pragma unroll
    for (int s=0;s<4;++s){
      bf0[s] = *(const short8*)(hp0 + s*32);
      bf1[s] = *(const short8*)(hp1 + s*32);
    }
    #pragma unroll 4
    for (int t=0;t<16;++t){
      float4v ac0 = {0.f,0.f,0.f,0.f}, ac1 = {0.f,0.f,0.f,0.f};
      #pragma unroll
      for (int s=0;s<4;++s){
        int row = t*16 + c;
        int byt = (row*256 + s*64 + q*16) ^ ((row&7)<<4);
        short8 af = *(const short8*)((const char*)wt + byt);
        ac0 = MFMA16(af, bf0[s], ac0);
        ac1 = MFMA16(af, bf1[s], ac1);
      }
      if (t < 8){
        int co = t*8 + q*2;
        *(uint2*)(hsb + (size_t)node0*64 + co) =
            make_uint2(pack2(ac0[0],ac0[1]), pack2(ac0[2],ac0[3]));
        if (v1) *(uint2*)(hsb + (size_t)node1*64 + co) =
            make_uint2(pack2(ac1[0],ac1[1]), pack2(ac1[2],ac1[3]));
      } else {
        int dd = (t-8)*16 + q*4;
        *(float4*)(hd + (size_t)node0*HID + dd) = make_float4(ac0[0],ac0[1],ac0[2],ac0[3]);
        if (v1) *(float4*)(hd + (size_t)node1*HID + dd) = make_float4(ac1[0],ac1[1],ac1[2],ac1[3]);
      }
    }
  }
}

// ---------------- GATv2 edge aggregation: 4 edges/wave, 16 lanes/edge -------
// R9-form (scalar math, 1-deep prefetch) reading combined 16B edge records.
__global__ __launch_bounds__(256) void k_edge(const unsigned* __restrict__ hsb,
    float* __restrict__ hdio, const unsigned* __restrict__ hbu,
    const int4* __restrict__ ecomb,
    const int* __restrict__ offs, const float* __restrict__ We,
    const float* __restrict__ att, const float* __restrict__ bias){
  int bid = xcd_swizzle(blockIdx.x, gridDim.x);
  int n = (bid*256 + (int)threadIdx.x) >> 6;
  if (n >= Nn) return;
  int lane = threadIdx.x & 63;
  int row = lane >> 4;      // edge slot 0..3
  int c   = lane & 15;      // dim group
  int d0  = 8*c;            // dims d0..d0+7, head = c>>2
  float we0[8], we1[8], at[8], xr[8];
  #pragma unroll
  for (int j=0;j<8;++j){
    we0[j] = We[d0+j];
    we1[j] = We[HID+d0+j];
    at[j]  = att[d0+j] * LOG2E;
  }
  *(float4*)(xr)   = *(const float4*)(hdio + (size_t)n*HID + d0);
  *(float4*)(xr+4) = *(const float4*)(hdio + (size_t)n*HID + d0 + 4);
  int e0 = offs[n], e1 = offs[n+1];
  float m = 0.f, ssum = 0.f;
  float acc[8];
  #pragma unroll
  for (int j=0;j<8;++j) acc[j] = 0.f;

  // 1-deep unconditional prefetch; ecomb padded by 16 entries past E2
  int4  rC = ecomb[e0 + row];
  uint4 xC = *(const uint4*)(hsb + ((size_t)(unsigned)rC.x<<6) + 4*c);
  bool  vC = (e0 + row) < e1;
  for (int e = e0; e < e1; e += 4){
    int en = e + 4 + row;
    int4  rN = ecomb[en];
    uint4 xN = *(const uint4*)(hsb + ((size_t)(unsigned)rN.x<<6) + 4*c);
    bool  vN = en < e1;
    float xl[8];
    xl[0]=bf_lo(xC.x); xl[1]=bf_hi(xC.x); xl[2]=bf_lo(xC.y); xl[3]=bf_hi(xC.y);
    xl[4]=bf_lo(xC.z); xl[5]=bf_hi(xC.z); xl[6]=bf_lo(xC.w); xl[7]=bf_hi(xC.w);
    float eCx = __int_as_float(rC.y), eCy = __int_as_float(rC.z);
    float dot = 0.f;
    #pragma unroll
    for (int j=0;j<8;++j){
      float z = fmaf(eCy, we1[j], fmaf(eCx, we0[j], xl[j] + xr[j]));
      z = fmaxf(z, SLOPE*z);
      dot = fmaf(z, at[j], dot);
    }
    float sc = red4_quad(dot);          // per-(edge-slot, head) score (log2 units)
    if (e == e0) m = __shfl(sc, lane & 15, 64);  // slot-0's score per head
    float p = exp2f(sc - m);
    p = vC ? p : 0.f;
    ssum += p;
    #pragma unroll
    for (int j=0;j<8;++j) acc[j] = fmaf(p, xl[j], acc[j]);
    rC=rN; xC=xN; vC=vN;
  }
  #pragma unroll
  for (int j=0;j<8;++j){
    acc[j] += __shfl_xor(acc[j], 16, 64);
    acc[j] += __shfl_xor(acc[j], 32, 64);
  }
  ssum += __shfl_xor(ssum, 16, 64);
  ssum += __shfl_xor(ssum, 32, 64);
  if (row == 0){
    float inv = 1.f/ssum;
    uint4 hu = *(const uint4*)(hbu + ((size_t)n<<6) + 4*c);
    float hr[8];
    hr[0]=bf_lo(hu.x); hr[1]=bf_hi(hu.x); hr[2]=bf_lo(hu.y); hr[3]=bf_hi(hu.y);
    hr[4]=bf_lo(hu.z); hr[5]=bf_hi(hu.z); hr[6]=bf_lo(hu.w); hr[7]=bf_hi(hu.w);
    float o[8];
    #pragma unroll
    for (int j=0;j<8;++j) o[j] = fmaf(acc[j], inv, bias[d0+j] + hr[j]);
    *(float4*)(hdio + (size_t)n*HID + d0)     = make_float4(o[0],o[1],o[2],o[3]);
    *(float4*)(hdio + (size_t)n*HID + d0 + 4) = make_float4(o[4],o[5],o[6],o[7]);
  }
}

// ---------------- GraphNorm reduce: per-(graph,dim) sum & sumsq ----------------
__global__ __launch_bounds__(128) void k_gn_reduce(const float* __restrict__ out,
    const int* __restrict__ gstart, float* __restrict__ gsum_, float* __restrict__ gsq_){
  int b = blockIdx.x >> 4, sub = blockIdx.x & 15;
  int ns = gstart[b], ne = gstart[b+1];
  int d = threadIdx.x;
  float s = 0.f, qq = 0.f;
  for (int n = ns + sub; n < ne; n += 16){
    float v = out[(size_t)n*HID + d];
    s += v; qq = fmaf(v, v, qq);
  }
  atomicAdd(&gsum_[b*HID + d], s);
  atomicAdd(&gsq_[b*HID + d], qq);
}

// ---------------- GraphNorm apply + ELU: wave per node ----------------
__global__ __launch_bounds__(256) void k_gn_apply(const float* __restrict__ out,
    const float* __restrict__ gsum_, const float* __restrict__ gsq_,
    const int* __restrict__ gstart, const int* __restrict__ batch,
    const float* __restrict__ gw, const float* __restrict__ gb,
    const float* __restrict__ gs,
    unsigned* __restrict__ hbu, float* __restrict__ emb){
  int n = (blockIdx.x*blockDim.x + threadIdx.x) >> 6;
  if (n >= Nn) return;
  int lane = threadIdx.x & 63;
  int b = batch[n];
  float icnt = 1.f / fmaxf((float)(gstart[b+1]-gstart[b]), 1.f);
  int d0 = 2*lane, d1 = d0+1;
  float2 x = *(const float2*)(out + (size_t)n*HID + d0);
  float mean0 = gsum_[b*HID+d0]*icnt, mean1 = gsum_[b*HID+d1]*icnt;
  float ms0 = mean0*gs[d0], ms1 = mean1*gs[d1];
  float var0 = gsq_[b*HID+d0]*icnt - ms0*(2.f*mean0 - ms0);
  float var1 = gsq_[b*HID+d1]*icnt - ms1*(2.f*mean1 - ms1);
  float rs0 = rsqrtf(fmaxf(var0, 0.f) + EPS);
  float rs1 = rsqrtf(fmaxf(var1, 0.f) + EPS);
  float y0 = gw[d0]*(x.x - ms0)*rs0 + gb[d0];
  float y1 = gw[d1]*(x.y - ms1)*rs1 + gb[d1];
  y0 = (y0 > 0.f) ? y0 : (__expf(y0) - 1.f);
  y1 = (y1 > 0.f) ? y1 : (__expf(y1) - 1.f);
  hbu[(size_t)n*64 + lane] = pack2(y0, y1);
  if (emb) *(float2*)(emb + (size_t)n*HID + d0) = make_float2(y0, y1);
}

// ---------------- pooling scores via MFMA + global max ----------------
__global__ __launch_bounds__(256) void k_pool_score(
    const unsigned* __restrict__ hbu, const unsigned* __restrict__ pw1img,
    const float* __restrict__ b1, const float* __restrict__ W2,
    float* __restrict__ score, unsigned* __restrict__ mkey){
  __shared__ unsigned wt[8192];  // 32 KiB, pre-swizzled image
  __shared__ float b1l[HID], w2l[HID];
  for (int i = threadIdx.x; i < 2048; i += 256)
    ((uint4*)wt)[i] = ((const uint4*)pw1img)[i];
  if (threadIdx.x < HID){ b1l[threadIdx.x] = b1[threadIdx.x]; w2l[threadIdx.x] = W2[threadIdx.x]; }
  __syncthreads();
  int wid = threadIdx.x >> 6, lane = threadIdx.x & 63;
  int q = lane >> 4, c = lane & 15;
  const unsigned short* hb = (const unsigned short*)hbu;
  float bmax = -1e30f;
  for (int p = blockIdx.x*4 + wid; p < NSTRIP; p += gridDim.x*4){
    int node = p*16 + c;
    short8 bf[4];
    const unsigned short* hp = hb + (size_t)node*HID + q*8;
    #pragma unroll
    for (int s=0;s<4;++s) bf[s] = *(const short8*)(hp + s*32);
    float part = 0.f;
    #pragma unroll
    for (int t=0;t<8;++t){
      float4v ac = {0.f,0.f,0.f,0.f};
      #pragma unroll
      for (int s=0;s<4;++s){
        int row = t*16 + c;
        int byt = (row*256 + s*64 + q*16) ^ ((row&7)<<4);
        ac = MFMA16(*(const short8*)((const char*)wt + byt), bf[s], ac);
      }
      int dim = t*16 + q*4;
      #pragma unroll
      for (int r=0;r<4;++r)
        part += tanh_fast(ac[r] + b1l[dim+r]) * w2l[dim+r];
    }
    part += __shfl_xor(part, 16, 64);
    part += __shfl_xor(part, 32, 64);
    if (q==0) score[node] = part;
    bmax = fmaxf(bmax, part);
  }
  #pragma unroll
  for (int o=32;o;o>>=1) bmax = fmaxf(bmax, __shfl_xor(bmax, o, 64));
  if (lane==0) atomicMax(mkey, fkey(bmax));
}

// ---------------- pooled accumulation per (graph,sub) ----------------
__global__ __launch_bounds__(128) void k_pool_reduce(const unsigned* __restrict__ hbu,
    const float* __restrict__ score, const unsigned* __restrict__ mkey,
    const int* __restrict__ gstart, float* __restrict__ gsum, float* __restrict__ total){
  int b = blockIdx.x >> 4, sub = blockIdx.x & 15;
  int ns = gstart[b], ne = gstart[b+1];
  float mx = fkeyinv(*mkey);
  int d = threadIdx.x;
  float acc = 0.f, es = 0.f;
  for (int n = ns + sub; n < ne; n += 16){
    float ev = __expf(score[n] - mx);
    unsigned u = hbu[(size_t)n*64 + (d>>1)];
    float hv = (d & 1) ? bf_hi(u) : bf_lo(u);
    acc = fmaf(ev, hv, acc);
    if (d==0) es += ev;
  }
  atomicAdd(&gsum[b*HID + d], acc);
  if (d==0) atomicAdd(total, es);
}

// ---------------- output mapper: one wave per graph ----------------
__global__ __launch_bounds__(64) void k_mapper(const float* __restrict__ gsum,
    const float* __restrict__ total,
    const float* __restrict__ W1, const float* __restrict__ b1,
    const float* __restrict__ g,  const float* __restrict__ bbv,
    const float* __restrict__ W2, const float* __restrict__ b2v,
    float* __restrict__ out0){
  int b = blockIdx.x, lane = threadIdx.x;
  float inv = 1.f/(*total);
  int d0 = 2*lane, d1 = d0+1;
  float gv0 = gsum[b*HID + d0]*inv, gv1 = gsum[b*HID + d1]*inv;
  float a0 = b1[d0], a1 = b1[d1];
  for (int i=0;i<HID;++i){
    float hv = lane_bcast((i&1) ? gv1 : gv0, i>>1);
    a0 = fmaf(hv, W1[i*HID + d0], a0);
    a1 = fmaf(hv, W1[i*HID + d1], a1);
  }
  a0 = fmaxf(a0, 0.f); a1 = fmaxf(a1, 0.f);
  float mu = wred_sum(a0+a1) * (1.f/HID);
  float c0 = a0-mu, c1 = a1-mu;
  float var = wred_sum(c0*c0 + c1*c1) * (1.f/HID);
  float rs = rsqrtf(var + EPS);
  float l0 = g[d0]*c0*rs + bbv[d0];
  float l1 = g[d1]*c1*rs + bbv[d1];
  float acc = b2v[lane];
  for (int j=0;j<HID;++j){
    float lv = lane_bcast((j&1) ? l1 : l0, j>>1);
    acc = fmaf(lv, W2[j*OUTD + lane], acc);
  }
  out0[b*OUTD + lane] = acc;
}

// =====================================================================
extern "C" void kernel_launch(void* const* d_in, const int* in_sizes, int n_in,
                              void* d_out, int out_size, void* d_ws, size_t ws_size,
                              hipStream_t stream){
  const float* x     = (const float*)d_in[0];
  const int*   ei    = (const int*)  d_in[1];
  const float* ea    = (const float*)d_in[2];
  const int*   batch = (const int*)  d_in[3];
  const float* encW  = (const float*)d_in[4];
  const float* encb  = (const float*)d_in[5];
  const float* encg  = (const float*)d_in[6];
  const float* encbb = (const float*)d_in[7];
  const float* gWsrc = (const float*)d_in[8];
  const float* gWdst = (const float*)d_in[9];
  const float* gWe   = (const float*)d_in[10];
  const float* gatt  = (const float*)d_in[11];
  const float* gbias = (const float*)d_in[12];
  const float* gnw   = (const float*)d_in[13];
  const float* gnb   = (const float*)d_in[14];
  const float* gns   = (const float*)d_in[15];
  const float* pW1   = (const float*)d_in[16];
  const float* pb1   = (const float*)d_in[17];
  const float* pW2   = (const float*)d_in[18];
  const float* mW1   = (const float*)d_in[19];
  const float* mb1   = (const float*)d_in[20];
  const float* mg    = (const float*)d_in[21];
  const float* mbb   = (const float*)d_in[22];
  const float* mW2   = (const float*)d_in[23];
  const float* mb2   = (const float*)d_in[24];

  char* w = (char*)d_ws;
  size_t off = 0;
  auto alloc = [&](size_t bytes)->char*{
    char* p = w + off;
    off += (bytes + 255) & ~(size_t)255;
    return p;
  };
  unsigned* hbu    = (unsigned*)alloc((size_t)Nn*64*4);    // bf16-packed h
  unsigned* hsb    = (unsigned*)alloc((size_t)Nn*64*4);    // bf16-packed hs
  float*    hd     = (float*)   alloc((size_t)Nn*HID*4);   // hd, then GAT 'out' in place
  int4*     ecomb  = (int4*)    alloc((size_t)(E2+16)*16); // {src, ea0, ea1, 0}
  int*      offs   = (int*)     alloc((size_t)(Nn+1)*4);
  int*      cursor = (int*)     alloc((size_t)Nn*4);
  int*      deg    = (int*)     alloc((size_t)Nn*4);
  int*      gstart = (int*)     alloc((size_t)(Bb+1)*4);
  float*    score  = (float*)   alloc((size_t)Nn*4);
  // zero-region: gsum | 3 layers × (gnsum|gnsq) — one memset
  float*    gsum   = (float*)   alloc((size_t)Bb*HID*4 * 7);
  float*    gnbase = gsum + Bb*HID;
  unsigned* wtimg  = (unsigned*)alloc((size_t)3*16384*4);  // pre-swizzled W_T images
  unsigned* pw1img = (unsigned*)alloc((size_t)8192*4);
  float*    scal   = (float*)   alloc(256); // [0]=eam0 [1]=eam1 [2]=total [3]=mkey
  float*    eam   = scal;
  float*    total = scal + 2;
  unsigned* mkey  = (unsigned*)(scal + 3);

  float* out_graph = (float*)d_out;
  float* out_node  = (float*)d_out + (size_t)Bb*OUTD;

  hipMemsetAsync(deg,  0, (size_t)Nn*4, stream);
  hipMemsetAsync(scal, 0, 256, stream);
  hipMemsetAsync(gsum, 0, (size_t)Bb*HID*4 * 7, stream);

  k_wprep<<<224, 256, 0, stream>>>(gWsrc, gWdst, pW1, wtimg, pw1img);
  k_encoder<<<Nn/4, 256, 0, stream>>>(x, encW, encb, encg, encbb, hbu);
  k_ea_mean<<<256, 256, 0, stream>>>(ea, eam);
  k_deg<<<(Ee+255)/256, 256, 0, stream>>>(ei, deg);
  k_scan<<<1, 1024, 0, stream>>>(deg, offs, cursor);
  k_scatter<<<(E2+16+255)/256, 256, 0, stream>>>(ei, ea, eam, cursor, ecomb);
  k_gstart<<<(Nn+255)/256, 256, 0, stream>>>(batch, gstart);

  for (int l = 0; l < 3; ++l){
    float* gnsum_l = gnbase + (size_t)l*2*Bb*HID;
    float* gnsq_l  = gnsum_l + Bb*HID;
    k_dualgemm<<<392, 256, 0, stream>>>(hbu, wtimg + (size_t)l*16384, hsb, hd);
    k_edge<<<Nn/4, 256, 0, stream>>>(hsb, hd, hbu, ecomb, offs,
                                     gWe + (size_t)l*2*HID,
                                     gatt + (size_t)l*4*32,
                                     gbias + (size_t)l*HID);
    k_gn_reduce<<<Bb*16, 128, 0, stream>>>(hd, gstart, gnsum_l, gnsq_l);
    k_gn_apply<<<Nn/4, 256, 0, stream>>>(hd, gnsum_l, gnsq_l, gstart, batch,
                                         gnw + (size_t)l*HID, gnb + (size_t)l*HID,
                                         gns + (size_t)l*HID, hbu,
                                         (l==2) ? out_node : (float*)nullptr);
  }

  k_pool_score<<<256, 256, 0, stream>>>(hbu, pw1img, pb1, pW2, score, mkey);
  k_pool_reduce<<<Bb*16, 128, 0, stream>>>(hbu, score, mkey, gstart, gsum, total);
  k_mapper<<<Bb, 64, 0, stream>>>(gsum, total, mW1, mb1, mg, mbb, mW2, mb2, out_graph);
}